// Round 14
// baseline (166.426 us; speedup 1.0000x reference)
//
#include <hip/hip_runtime.h>
#include <math.h>

// Problem constants (from reference): B=64, Q=900, T=128, NUM_CLASSES=13
#define B_    64
#define Q_    900
#define T_    128
#define NCLS  13
#define NCLS1 14
#define NTH   256
#define NWV   (NTH / 64)
#define NK    15          // wave0 scan: col q = lane + 64*k, k<NK

// Block-wide f64 sum; result valid on tid 0. All threads must call.
__device__ __forceinline__ double blockSum(double v, double* sAcc, int tid) {
#pragma unroll
    for (int off = 32; off > 0; off >>= 1) v += __shfl_down(v, off);
    if ((tid & 63) == 0) sAcc[tid >> 6] = v;
    __syncthreads();
    if (tid == 0) {
#pragma unroll
        for (int w = 1; w < NWV; ++w) v += sAcc[w];
    }
    __syncthreads();
    return v;
}

// f32 cost entry, identical op order to the jnp reference:
// (|dx|+|dy|+|dz|+|dw| summed left-to-right) - prob[lab].
__device__ __forceinline__ float costQ(const float4 p4, const float4 t4, const float pr) {
    float cb = fabsf(p4.x - t4.x);
    cb = cb + fabsf(p4.y - t4.y);
    cb = cb + fabsf(p4.z - t4.z);
    cb = cb + fabsf(p4.w - t4.w);
    return cb - pr;
}

// ---- DPP full-wave min reductions (row_shr + row_bcast chain) ----
// Verified exact on R11/R13 (absmax 0). Uniform result via readlane(63).
#define DPP_ROW_SHR1 0x111
#define DPP_ROW_SHR2 0x112
#define DPP_ROW_SHR4 0x114
#define DPP_ROW_SHR8 0x118
#define DPP_BCAST15  0x142
#define DPP_BCAST31  0x143

__device__ __forceinline__ float waveMinF32(float x) {
    const int INFI = 0x7f800000;                       // +inf bits
    float f = x;
#define MRED(C) { const int o = __builtin_amdgcn_update_dpp(INFI, __float_as_int(f), C, 0xf, 0xf, false); \
                  f = fminf(f, __int_as_float(o)); }
    MRED(DPP_ROW_SHR1) MRED(DPP_ROW_SHR2) MRED(DPP_ROW_SHR4) MRED(DPP_ROW_SHR8)
    MRED(DPP_BCAST15)  MRED(DPP_BCAST31)
#undef MRED
    return __int_as_float(__builtin_amdgcn_readlane(__float_as_int(f), 63));
}

__device__ __forceinline__ int waveMinI32(int x) {
    int f = x;
#define MRED(C) { const int o = __builtin_amdgcn_update_dpp(0x7fffffff, f, C, 0xf, 0xf, false); \
                  f = (o < f) ? o : f; }
    MRED(DPP_ROW_SHR1) MRED(DPP_ROW_SHR2) MRED(DPP_ROW_SHR4) MRED(DPP_ROW_SHR8)
    MRED(DPP_BCAST15)  MRED(DPP_BCAST31)
#undef MRED
    return __builtin_amdgcn_readlane(f, 63);
}

// One block per image. R13-proven structure. R14 delta: the popped column's
// matched row is tracked IN the scan (bestRow = cmr[k], each lane's register
// snapshot of sP for its own columns — constant within a pass) and resolved
// post-ballot with a single readlane, removing the dependent sP[winq] LDS
// read (~120 cyc) from the pop critical path. R12's failure mode (post-
// reduction select chains / serialized readlanes for row data) is avoided:
// row data stays in pipelined LDS reads. Decision stream bit-identical to
// R6/R11/R13 => absmax 0.
extern "C" __global__ __launch_bounds__(NTH, 1)
void detr_hungarian_loss(const float* __restrict__ pc,    // [B,Q,14]
                         const float* __restrict__ pbx,   // [B,Q,4]
                         const int*   __restrict__ tl,    // [B,T]
                         const float* __restrict__ tbx,   // [B,T,4]
                         float* __restrict__ out)         // [1], poisoned 0xAA
{
    const int b   = blockIdx.x;
    const int tid = threadIdx.x;

    __shared__ float  sProb[Q_ * NCLS];   // softmax probs, classes 0..12
    __shared__ float  sLse[Q_];           // logsumexp per query (for CE)
    __shared__ float4 sPb4[Q_];           // predicted boxes
    __shared__ float4 sTb4[T_];           // target boxes
    __shared__ int    sLab[T_];           // target labels
    __shared__ float  sU[T_];             // row duals (f32)
    __shared__ int    sP[Q_];             // col -> row+1, 0 = free
    __shared__ int    sWay[Q_];           // parent cols (per pass); reused as tc[]
    __shared__ int    sAmin[T_];          // row -> argmin column
    __shared__ int    sFree[T_];
    __shared__ int    sNF;
    __shared__ int    sPred[T_];          // target t -> matched query
    __shared__ double sAcc[NWV];

    const float FINF = __builtin_inff();

    const float* pcb = pc  + (size_t)b * Q_ * NCLS1;
    const float* pbb = pbx + (size_t)b * Q_ * 4;
    const float* tbb = tbx + (size_t)b * T_ * 4;
    const int*   tlb = tl  + (size_t)b * T_;

    // ---- stage inputs + f32 softmax (same op order as jax.nn.softmax) ----
    for (int q = tid; q < Q_; q += NTH) {
        float x[NCLS1];
#pragma unroll
        for (int c = 0; c < NCLS1; ++c) x[c] = pcb[q * NCLS1 + c];
        float mx = x[0];
#pragma unroll
        for (int c = 1; c < NCLS1; ++c) mx = fmaxf(mx, x[c]);
        float ex[NCLS1];
        float sum = 0.f;
#pragma unroll
        for (int c = 0; c < NCLS1; ++c) { ex[c] = expf(x[c] - mx); sum += ex[c]; }
#pragma unroll
        for (int c = 0; c < NCLS; ++c) sProb[q * NCLS + c] = ex[c] / sum;
        sLse[q] = mx + logf(sum);
        sPb4[q] = reinterpret_cast<const float4*>(pbb)[q];
        sP[q] = 0;
    }
    for (int t = tid; t < T_; t += NTH) {
        sLab[t] = tlb[t];
        sTb4[t] = reinterpret_cast<const float4*>(tbb)[t];
    }
    __syncthreads();

    // ---- phase 1: row minima u[r] = min_j cost[r][j] + argmin column ----
    {
        const int r    = tid >> 1;        // 0..127, two threads per row
        const int half = tid & 1;
        const float4 t4  = sTb4[r];
        const int    lab = sLab[r];
        float bv = FINF;
        int   bj = Q_;
        const int q0 = half * (Q_ / 2);
        for (int q = q0; q < q0 + (Q_ / 2); ++q) {
            const float c = costQ(sPb4[q], t4, sProb[q * NCLS + lab]);
            if (c < bv) { bv = c; bj = q; }
        }
        const float ov = __shfl_xor(bv, 1);
        const int   oj = __shfl_xor(bj, 1);
        if (ov < bv || (ov == bv && oj < bj)) { bv = ov; bj = oj; }
        if (half == 0) { sU[r] = bv; sAmin[r] = bj; }
    }
    __syncthreads();

    // ---- greedy zero-reduced-cost assignment (R6-identical, serial) ----
    if (tid == 0) {
        int nf = 0;
        for (int r = 0; r < T_; ++r) {
            const int j = sAmin[r];
            if (sP[j] == 0) sP[j] = r + 1;
            else            sFree[nf++] = r;
        }
        sNF = nf;
    }
    __syncthreads();

    // ============ wave 0 only: deferred-dual SSP ============
    if (tid < 64) {
        const int lane = tid;
        const unsigned validMask = (lane < (Q_ - 64 * (NK - 1))) ? ((1u << NK) - 1u)
                                                                 : ((1u << (NK - 1)) - 1u);
        float4 pbr[NK];                   // owned predicted boxes
        float  v[NK];                     // owned column duals
        int    cmr[NK];                   // owned cols -> row+1 (sP snapshot)
#pragma unroll
        for (int k = 0; k < NK; ++k) {
            const int q = (k << 6) + lane;
            pbr[k] = (q < Q_) ? sPb4[q] : make_float4(0.f, 0.f, 0.f, 0.f);
            v[k]   = 0.f;
            cmr[k] = (q < Q_) ? sP[q] : 0;
        }
        const int nf = sNF;

        for (int fi = 0; fi < nf; ++fi) {
            const int rf = sFree[fi];
            float minv[NK];
            int   way[NK];
#pragma unroll
            for (int k = 0; k < NK; ++k) { minv[k] = FINF; way[k] = -1; }
            unsigned usedM   = ~validMask;
            unsigned poppedM = 0;
            int   i0row = rf;
            float dcur  = 0.f;
            int   jprev = -1;             // root marker
            float dT = 0.f; int jT = -1;

            for (int it = 0; it < 200; ++it) {
                const float  u0   = sU[i0row];
                const float4 t4   = sTb4[i0row];
                const int    lab  = sLab[i0row];
                const float  base = dcur - u0;

                float bestv   = FINF;
                int   bestq   = 1 << 29;
                int   bestRow = 0;        // matched row of bestq (from cmr)
#pragma unroll
                for (int k = 0; k < NK; ++k) {
                    if (!((usedM >> k) & 1u)) {
                        const int   q    = (k << 6) + lane;
                        const float cost = costQ(pbr[k], t4, sProb[q * NCLS + lab]);
                        const float cur  = base + (cost - v[k]);   // R6 association
                        if (cur < minv[k]) { minv[k] = cur; way[k] = jprev; }
                        if (minv[k] < bestv) {
                            bestv = minv[k]; bestq = q; bestRow = cmr[k];
                        }
                    }
                }
                // DPP wave value-min, ballot index fast path (R13-proven),
                // matched row via readlane from the winner's register cache.
                const float winv = waveMinF32(bestv);
                const unsigned long long tm = __ballot(bestv == winv);
                int winq, rowm;
                if (__popcll(tm) == 1) {
                    const int wl = (int)__builtin_ctzll(tm);
                    winq = __builtin_amdgcn_readlane(bestq,   wl);
                    rowm = __builtin_amdgcn_readlane(bestRow, wl);
                } else {
                    const int cand = (bestv == winv) ? bestq : 0x7fffffff;
                    winq = waveMinI32(cand);     // smallest column (R6 ties)
                    // bestq values are distinct across lanes (col≡lane mod 64)
                    const unsigned long long t2 = __ballot(bestq == winq);
                    const int wl2 = (int)__builtin_ctzll(t2);
                    rowm = __builtin_amdgcn_readlane(bestRow, wl2);
                }

                if ((winq & 63) == lane) usedM |= 1u << (winq >> 6);  // freeze
                __builtin_amdgcn_wave_barrier();
                if (rowm == 0) { dT = winv; jT = winq; break; }   // free col: done
                if ((winq & 63) == lane) poppedM |= 1u << (winq >> 6);
                jprev = winq; i0row = rowm - 1; dcur = winv;
            }

            // flush way regs (augment only reads cols improved this pass)
#pragma unroll
            for (int k = 0; k < NK; ++k) {
                if ((validMask >> k) & 1u) sWay[(k << 6) + lane] = way[k];
            }
            // deferred dual updates (== e-maxx incremental totals), pre-augment
#pragma unroll
            for (int k = 0; k < NK; ++k) {
                if ((poppedM >> k) & 1u) {
                    const int row = cmr[k] - 1;       // distinct rows, no race
                    sU[row] += dT - minv[k];
                    v[k]    += minv[k] - dT;
                }
            }
            if (lane == 0) sU[rf] += dT;
            __builtin_amdgcn_wave_barrier();
            if (lane == 0 && jT >= 0) {                // augment along parents
                int jj = jT, guard = 0;
                while (guard++ < 200) {
                    const int jp = sWay[jj];
                    if (jp < 0) { sP[jj] = rf + 1; break; }
                    sP[jj] = sP[jp];
                    jj = jp;
                }
            }
            __builtin_amdgcn_wave_barrier();
            // refresh sP snapshot (matching changed only along augment path)
#pragma unroll
            for (int k = 0; k < NK; ++k) {
                if ((validMask >> k) & 1u) cmr[k] = sP[(k << 6) + lane];
            }
            __builtin_amdgcn_wave_barrier();
        }
    }
    __syncthreads();

    // ---- extract matching: pred query for each target ----
    for (int q = tid; q < Q_; q += NTH) {
        const int pi = sP[q];
        if (pi > 0) sPred[pi - 1] = q;
    }
    __syncthreads();

    // ---- tc[] (reuse sWay): NUM_CLASSES default, matched queries get label ----
    int* sTc = sWay;
    for (int q = tid; q < Q_; q += NTH) sTc[q] = NCLS;
    __syncthreads();
    for (int t = tid; t < T_; t += NTH) sTc[sPred[t]] = sLab[t];  // sPred distinct
    __syncthreads();

    // ---- weighted CE over all queries ----
    double swn = 0.0, sw = 0.0;
    for (int q = tid; q < Q_; q += NTH) {
        const int   c   = sTc[q];
        const float xv  = pcb[q * NCLS1 + c];
        const float nll = sLse[q] - xv;              // -log_softmax[tc]
        const double w  = (c == NCLS) ? (double)0.05f : 1.0;
        swn += w * (double)nll;
        sw  += w;
    }

    // ---- bbox L1 + GIoU over matched pairs ----
    double l1s = 0.0, gs = 0.0;
    for (int t = tid; t < T_; t += NTH) {
        const int q = sPred[t];
        const float4 p4 = sPb4[q];
        const float4 t4 = sTb4[t];
        l1s += (double)fabsf(p4.x - t4.x) + (double)fabsf(p4.y - t4.y)
             + (double)fabsf(p4.z - t4.z) + (double)fabsf(p4.w - t4.w);
        const float ax1 = p4.x - 0.5f * p4.z, ay1 = p4.y - 0.5f * p4.w;
        const float ax2 = p4.x + 0.5f * p4.z, ay2 = p4.y + 0.5f * p4.w;
        const float bx1 = t4.x - 0.5f * t4.z, by1 = t4.y - 0.5f * t4.w;
        const float bx2 = t4.x + 0.5f * t4.z, by2 = t4.y + 0.5f * t4.w;
        const double a1 = (double)(ax2 - ax1) * (double)(ay2 - ay1);
        const double a2 = (double)(bx2 - bx1) * (double)(by2 - by1);
        const double ltx = fmax((double)ax1, (double)bx1);
        const double lty = fmax((double)ay1, (double)by1);
        const double rbx = fmin((double)ax2, (double)bx2);
        const double rby = fmin((double)ay2, (double)by2);
        const double iw = fmax(rbx - ltx, 0.0), ih = fmax(rby - lty, 0.0);
        const double inter = iw * ih;
        const double uni   = a1 + a2 - inter;
        const double iou   = inter / uni;
        const double cx1 = fmin((double)ax1, (double)bx1);
        const double cy1 = fmin((double)ay1, (double)by1);
        const double cx2 = fmax((double)ax2, (double)bx2);
        const double cy2 = fmax((double)ay2, (double)by2);
        const double ac  = (cx2 - cx1) * (cy2 - cy1);
        const double giou = iou - (ac - uni) / ac;
        gs += 1.0 - giou;
    }

    const double swnT = blockSum(swn, sAcc, tid);
    const double swT  = blockSum(sw,  sAcc, tid);
    const double l1T  = blockSum(l1s, sAcc, tid);
    const double gsT  = blockSum(gs,  sAcc, tid);
    if (tid == 0) {
        const double cls = swnT / swT;
        const double bb  = 5.0 * (l1T / (double)(T_ * 4)) + 2.0 * (gsT / (double)T_);
        const double mine = (cls + bb) / 8192.0;
        // fused finalize: CAS converts the 0xAA poison to 0.0 exactly once
        // (each block CASes before its own add; no spin), then atomic f32 sum.
        atomicCAS((unsigned int*)out, 0xAAAAAAAAu, 0u);
        atomicAdd(out, (float)mine);
    }
}

extern "C" void kernel_launch(void* const* d_in, const int* in_sizes, int n_in,
                              void* d_out, int out_size, void* d_ws, size_t ws_size,
                              hipStream_t stream) {
    const float* pc  = (const float*)d_in[0];   // predicted_class [64,900,14]
    const float* pbx = (const float*)d_in[1];   // predicted_bbox  [64,900,4]
    const int*   tl  = (const int*)  d_in[2];   // target_labels   [64,128]
    const float* tbx = (const float*)d_in[3];   // target_boxes    [64,128,4]
    (void)in_sizes; (void)n_in; (void)out_size; (void)d_ws; (void)ws_size;

    detr_hungarian_loss<<<dim3(B_), dim3(NTH), 0, stream>>>(pc, pbx, tl, tbx,
                                                            (float*)d_out);
}

// Round 15
// 161.461 us; speedup vs baseline: 1.0308x; 1.0308x over previous
//
#include <hip/hip_runtime.h>
#include <math.h>

// Problem constants (from reference): B=64, Q=900, T=128, NUM_CLASSES=13
#define B_    64
#define Q_    900
#define T_    128
#define NCLS  13
#define NCLS1 14
#define NTH   256
#define NWV   (NTH / 64)
#define NK    15          // wave0 scan: col q = lane + 64*k, k<NK

// Block-wide f64 sum; result valid on tid 0. All threads must call.
__device__ __forceinline__ double blockSum(double v, double* sAcc, int tid) {
#pragma unroll
    for (int off = 32; off > 0; off >>= 1) v += __shfl_down(v, off);
    if ((tid & 63) == 0) sAcc[tid >> 6] = v;
    __syncthreads();
    if (tid == 0) {
#pragma unroll
        for (int w = 1; w < NWV; ++w) v += sAcc[w];
    }
    __syncthreads();
    return v;
}

// f32 cost entry, identical op order to the jnp reference:
// (|dx|+|dy|+|dz|+|dw| summed left-to-right) - prob[lab].
__device__ __forceinline__ float costQ(const float4 p4, const float4 t4, const float pr) {
    float cb = fabsf(p4.x - t4.x);
    cb = cb + fabsf(p4.y - t4.y);
    cb = cb + fabsf(p4.z - t4.z);
    cb = cb + fabsf(p4.w - t4.w);
    return cb - pr;
}

// ---- DPP full-wave min reductions (row_shr + row_bcast chain) ----
// Verified exact on R11/R13 (absmax 0). Uniform result via readlane(63).
#define DPP_ROW_SHR1 0x111
#define DPP_ROW_SHR2 0x112
#define DPP_ROW_SHR4 0x114
#define DPP_ROW_SHR8 0x118
#define DPP_BCAST15  0x142
#define DPP_BCAST31  0x143

__device__ __forceinline__ float waveMinF32(float x) {
    const int INFI = 0x7f800000;                       // +inf bits
    float f = x;
#define MRED(C) { const int o = __builtin_amdgcn_update_dpp(INFI, __float_as_int(f), C, 0xf, 0xf, false); \
                  f = fminf(f, __int_as_float(o)); }
    MRED(DPP_ROW_SHR1) MRED(DPP_ROW_SHR2) MRED(DPP_ROW_SHR4) MRED(DPP_ROW_SHR8)
    MRED(DPP_BCAST15)  MRED(DPP_BCAST31)
#undef MRED
    return __int_as_float(__builtin_amdgcn_readlane(__float_as_int(f), 63));
}

__device__ __forceinline__ int waveMinI32(int x) {
    int f = x;
#define MRED(C) { const int o = __builtin_amdgcn_update_dpp(0x7fffffff, f, C, 0xf, 0xf, false); \
                  f = (o < f) ? o : f; }
    MRED(DPP_ROW_SHR1) MRED(DPP_ROW_SHR2) MRED(DPP_ROW_SHR4) MRED(DPP_ROW_SHR8)
    MRED(DPP_BCAST15)  MRED(DPP_BCAST31)
#undef MRED
    return __builtin_amdgcn_readlane(f, 63);
}

// One block per image. R13 == measured best (main 106.3 us, absmax 0).
// Structure: staging + row-minima on 256 threads; greedy zero-reduced-cost
// init; wave-0 deferred-dual SSP, all-f32 distances, column state in
// registers; DPP wave value-min + ballot index fast path (exact i32 DPP min
// fallback on value-ties = smallest column, np.argmin semantics).
// R12 (readlane row caching) and R14 (in-scan row tracking) both regressed:
// the scan is issue-bound and the pipelined LDS reads were already optimal.
extern "C" __global__ __launch_bounds__(NTH, 1)
void detr_hungarian_loss(const float* __restrict__ pc,    // [B,Q,14]
                         const float* __restrict__ pbx,   // [B,Q,4]
                         const int*   __restrict__ tl,    // [B,T]
                         const float* __restrict__ tbx,   // [B,T,4]
                         float* __restrict__ out)         // [1], poisoned 0xAA
{
    const int b   = blockIdx.x;
    const int tid = threadIdx.x;

    __shared__ float  sProb[Q_ * NCLS];   // softmax probs, classes 0..12
    __shared__ float  sLse[Q_];           // logsumexp per query (for CE)
    __shared__ float4 sPb4[Q_];           // predicted boxes
    __shared__ float4 sTb4[T_];           // target boxes
    __shared__ int    sLab[T_];           // target labels
    __shared__ float  sU[T_];             // row duals (f32)
    __shared__ int    sP[Q_];             // col -> row+1, 0 = free
    __shared__ int    sWay[Q_];           // parent cols (per pass); reused as tc[]
    __shared__ int    sAmin[T_];          // row -> argmin column
    __shared__ int    sFree[T_];
    __shared__ int    sNF;
    __shared__ int    sPred[T_];          // target t -> matched query
    __shared__ double sAcc[NWV];

    const float FINF = __builtin_inff();

    const float* pcb = pc  + (size_t)b * Q_ * NCLS1;
    const float* pbb = pbx + (size_t)b * Q_ * 4;
    const float* tbb = tbx + (size_t)b * T_ * 4;
    const int*   tlb = tl  + (size_t)b * T_;

    // ---- stage inputs + f32 softmax (same op order as jax.nn.softmax) ----
    for (int q = tid; q < Q_; q += NTH) {
        float x[NCLS1];
#pragma unroll
        for (int c = 0; c < NCLS1; ++c) x[c] = pcb[q * NCLS1 + c];
        float mx = x[0];
#pragma unroll
        for (int c = 1; c < NCLS1; ++c) mx = fmaxf(mx, x[c]);
        float ex[NCLS1];
        float sum = 0.f;
#pragma unroll
        for (int c = 0; c < NCLS1; ++c) { ex[c] = expf(x[c] - mx); sum += ex[c]; }
#pragma unroll
        for (int c = 0; c < NCLS; ++c) sProb[q * NCLS + c] = ex[c] / sum;
        sLse[q] = mx + logf(sum);
        sPb4[q] = reinterpret_cast<const float4*>(pbb)[q];
        sP[q] = 0;
    }
    for (int t = tid; t < T_; t += NTH) {
        sLab[t] = tlb[t];
        sTb4[t] = reinterpret_cast<const float4*>(tbb)[t];
    }
    __syncthreads();

    // ---- phase 1: row minima u[r] = min_j cost[r][j] + argmin column ----
    {
        const int r    = tid >> 1;        // 0..127, two threads per row
        const int half = tid & 1;
        const float4 t4  = sTb4[r];
        const int    lab = sLab[r];
        float bv = FINF;
        int   bj = Q_;
        const int q0 = half * (Q_ / 2);
        for (int q = q0; q < q0 + (Q_ / 2); ++q) {
            const float c = costQ(sPb4[q], t4, sProb[q * NCLS + lab]);
            if (c < bv) { bv = c; bj = q; }
        }
        const float ov = __shfl_xor(bv, 1);
        const int   oj = __shfl_xor(bj, 1);
        if (ov < bv || (ov == bv && oj < bj)) { bv = ov; bj = oj; }
        if (half == 0) { sU[r] = bv; sAmin[r] = bj; }
    }
    __syncthreads();

    // ---- greedy zero-reduced-cost assignment (R6-identical, serial) ----
    if (tid == 0) {
        int nf = 0;
        for (int r = 0; r < T_; ++r) {
            const int j = sAmin[r];
            if (sP[j] == 0) sP[j] = r + 1;
            else            sFree[nf++] = r;
        }
        sNF = nf;
    }
    __syncthreads();

    // ============ wave 0 only: deferred-dual SSP ============
    if (tid < 64) {
        const int lane = tid;
        const unsigned validMask = (lane < (Q_ - 64 * (NK - 1))) ? ((1u << NK) - 1u)
                                                                 : ((1u << (NK - 1)) - 1u);
        float4 pbr[NK];                   // owned predicted boxes
        float  v[NK];                     // owned column duals
#pragma unroll
        for (int k = 0; k < NK; ++k) {
            const int q = (k << 6) + lane;
            pbr[k] = (q < Q_) ? sPb4[q] : make_float4(0.f, 0.f, 0.f, 0.f);
            v[k] = 0.f;
        }
        const int nf = sNF;

        for (int fi = 0; fi < nf; ++fi) {
            const int rf = sFree[fi];
            float minv[NK];
            int   way[NK];
#pragma unroll
            for (int k = 0; k < NK; ++k) { minv[k] = FINF; way[k] = -1; }
            unsigned usedM   = ~validMask;
            unsigned poppedM = 0;
            int   i0row = rf;
            float dcur  = 0.f;
            int   jprev = -1;             // root marker
            float dT = 0.f; int jT = -1;

            for (int it = 0; it < 200; ++it) {
                const float  u0   = sU[i0row];
                const float4 t4   = sTb4[i0row];
                const int    lab  = sLab[i0row];
                const float  base = dcur - u0;

                float bestv = FINF;
                int   bestq = 1 << 29;
#pragma unroll
                for (int k = 0; k < NK; ++k) {
                    if (!((usedM >> k) & 1u)) {
                        const int   q    = (k << 6) + lane;
                        const float cost = costQ(pbr[k], t4, sProb[q * NCLS + lab]);
                        const float cur  = base + (cost - v[k]);   // R6 association
                        if (cur < minv[k]) { minv[k] = cur; way[k] = jprev; }
                        if (minv[k] < bestv) { bestv = minv[k]; bestq = q; }
                    }
                }
                // DPP wave min, then ballot fast path for the index:
                // single holder of the min (common) -> one readlane; ties ->
                // exact i32 DPP min (smallest column, same as R6 tie-break).
                const float winv = waveMinF32(bestv);
                const unsigned long long tm = __ballot(bestv == winv);
                int winq;
                if (__popcll(tm) == 1) {
                    winq = __builtin_amdgcn_readlane(bestq, (int)__builtin_ctzll(tm));
                } else {
                    const int cand = (bestv == winv) ? bestq : 0x7fffffff;
                    winq = waveMinI32(cand);
                }

                if ((winq & 63) == lane) usedM |= 1u << (winq >> 6);  // freeze
                const int rowm = sP[winq];
                __builtin_amdgcn_wave_barrier();
                if (rowm == 0) { dT = winv; jT = winq; break; }   // free col: done
                if ((winq & 63) == lane) poppedM |= 1u << (winq >> 6);
                jprev = winq; i0row = rowm - 1; dcur = winv;
            }

            // flush way regs (augment only reads cols improved this pass)
#pragma unroll
            for (int k = 0; k < NK; ++k) {
                if ((validMask >> k) & 1u) sWay[(k << 6) + lane] = way[k];
            }
            // deferred dual updates (== e-maxx incremental totals), pre-augment
#pragma unroll
            for (int k = 0; k < NK; ++k) {
                if ((poppedM >> k) & 1u) {
                    const int q   = (k << 6) + lane;
                    const int row = sP[q] - 1;        // distinct rows, no race
                    sU[row] += dT - minv[k];
                    v[k]    += minv[k] - dT;
                }
            }
            if (lane == 0) sU[rf] += dT;
            __builtin_amdgcn_wave_barrier();
            if (lane == 0 && jT >= 0) {                // augment along parents
                int jj = jT, guard = 0;
                while (guard++ < 200) {
                    const int jp = sWay[jj];
                    if (jp < 0) { sP[jj] = rf + 1; break; }
                    sP[jj] = sP[jp];
                    jj = jp;
                }
            }
            __builtin_amdgcn_wave_barrier();
        }
    }
    __syncthreads();

    // ---- extract matching: pred query for each target ----
    for (int q = tid; q < Q_; q += NTH) {
        const int pi = sP[q];
        if (pi > 0) sPred[pi - 1] = q;
    }
    __syncthreads();

    // ---- tc[] (reuse sWay): NUM_CLASSES default, matched queries get label ----
    int* sTc = sWay;
    for (int q = tid; q < Q_; q += NTH) sTc[q] = NCLS;
    __syncthreads();
    for (int t = tid; t < T_; t += NTH) sTc[sPred[t]] = sLab[t];  // sPred distinct
    __syncthreads();

    // ---- weighted CE over all queries ----
    double swn = 0.0, sw = 0.0;
    for (int q = tid; q < Q_; q += NTH) {
        const int   c   = sTc[q];
        const float xv  = pcb[q * NCLS1 + c];
        const float nll = sLse[q] - xv;              // -log_softmax[tc]
        const double w  = (c == NCLS) ? (double)0.05f : 1.0;
        swn += w * (double)nll;
        sw  += w;
    }

    // ---- bbox L1 + GIoU over matched pairs ----
    double l1s = 0.0, gs = 0.0;
    for (int t = tid; t < T_; t += NTH) {
        const int q = sPred[t];
        const float4 p4 = sPb4[q];
        const float4 t4 = sTb4[t];
        l1s += (double)fabsf(p4.x - t4.x) + (double)fabsf(p4.y - t4.y)
             + (double)fabsf(p4.z - t4.z) + (double)fabsf(p4.w - t4.w);
        const float ax1 = p4.x - 0.5f * p4.z, ay1 = p4.y - 0.5f * p4.w;
        const float ax2 = p4.x + 0.5f * p4.z, ay2 = p4.y + 0.5f * p4.w;
        const float bx1 = t4.x - 0.5f * t4.z, by1 = t4.y - 0.5f * t4.w;
        const float bx2 = t4.x + 0.5f * t4.z, by2 = t4.y + 0.5f * t4.w;
        const double a1 = (double)(ax2 - ax1) * (double)(ay2 - ay1);
        const double a2 = (double)(bx2 - bx1) * (double)(by2 - by1);
        const double ltx = fmax((double)ax1, (double)bx1);
        const double lty = fmax((double)ay1, (double)by1);
        const double rbx = fmin((double)ax2, (double)bx2);
        const double rby = fmin((double)ay2, (double)by2);
        const double iw = fmax(rbx - ltx, 0.0), ih = fmax(rby - lty, 0.0);
        const double inter = iw * ih;
        const double uni   = a1 + a2 - inter;
        const double iou   = inter / uni;
        const double cx1 = fmin((double)ax1, (double)bx1);
        const double cy1 = fmin((double)ay1, (double)by1);
        const double cx2 = fmax((double)ax2, (double)bx2);
        const double cy2 = fmax((double)ay2, (double)by2);
        const double ac  = (cx2 - cx1) * (cy2 - cy1);
        const double giou = iou - (ac - uni) / ac;
        gs += 1.0 - giou;
    }

    const double swnT = blockSum(swn, sAcc, tid);
    const double swT  = blockSum(sw,  sAcc, tid);
    const double l1T  = blockSum(l1s, sAcc, tid);
    const double gsT  = blockSum(gs,  sAcc, tid);
    if (tid == 0) {
        const double cls = swnT / swT;
        const double bb  = 5.0 * (l1T / (double)(T_ * 4)) + 2.0 * (gsT / (double)T_);
        const double mine = (cls + bb) / 8192.0;
        // fused finalize: CAS converts the 0xAA poison to 0.0 exactly once
        // (each block CASes before its own add; no spin), then atomic f32 sum.
        atomicCAS((unsigned int*)out, 0xAAAAAAAAu, 0u);
        atomicAdd(out, (float)mine);
    }
}

extern "C" void kernel_launch(void* const* d_in, const int* in_sizes, int n_in,
                              void* d_out, int out_size, void* d_ws, size_t ws_size,
                              hipStream_t stream) {
    const float* pc  = (const float*)d_in[0];   // predicted_class [64,900,14]
    const float* pbx = (const float*)d_in[1];   // predicted_bbox  [64,900,4]
    const int*   tl  = (const int*)  d_in[2];   // target_labels   [64,128]
    const float* tbx = (const float*)d_in[3];   // target_boxes    [64,128,4]
    (void)in_sizes; (void)n_in; (void)out_size; (void)d_ws; (void)ws_size;

    detr_hungarian_loss<<<dim3(B_), dim3(NTH), 0, stream>>>(pc, pbx, tl, tbx,
                                                            (float*)d_out);
}